// Round 1
// baseline (905.438 us; speedup 1.0000x reference)
//
#include <hip/hip_runtime.h>

// Shapes: B=8, C=256, H=W=32 -> S=1024 tokens; NH=8, DK=256; qkv dim 6144.
#define BB   8
#define CCH  256
#define SS   1024
#define NH   8
#define DK   256
#define NQKV 6144   // NH*DK*3
#define SCALE 0.0625f

using frag8 = __attribute__((ext_vector_type(8))) short;   // 8 bf16 (4 VGPRs)
using f32x4 = __attribute__((ext_vector_type(4))) float;   // MFMA acc

__device__ __forceinline__ unsigned short f2bf(float f) {
    unsigned int u = __float_as_uint(f);
    unsigned int r = (u + 0x7FFFu + ((u >> 16) & 1u)) >> 16;   // RNE
    return (unsigned short)r;
}
__device__ __forceinline__ float bf2f(unsigned short h) {
    return __uint_as_float(((unsigned int)h) << 16);
}

// ---------------------------------------------------------------------------
// K1: qkv = xt @ Wp + bp.   A[m,k] = x[b, k, s] (m = b*1024+s), B = Wp [256,6144].
// 128x128 tile, 8x8 per thread. Writes q,k as bf16 [BH,S,DK]; v TRANSPOSED
// bf16 [BH,DK,S] so K2's PV B-operand is key-contiguous.
// n-tiles (128-wide) never cross head (768) or q/k/v (256) boundaries: both are
// multiples of 128.
// ---------------------------------------------------------------------------
__global__ __launch_bounds__(256) void k1_qkv(
    const float* __restrict__ x, const float* __restrict__ Wp,
    const float* __restrict__ bp,
    unsigned short* __restrict__ qb, unsigned short* __restrict__ kb,
    unsigned short* __restrict__ vb)
{
    __shared__ float As[16][128];
    __shared__ float Bs[16][128];
    const int t  = threadIdx.x;
    const int n0 = blockIdx.x * 128;          // 48 tiles over 6144
    const int m0 = blockIdx.y * 128;          // 64 tiles over 8192
    const int b  = m0 >> 10;
    const int s0 = m0 & 1023;
    const int tx = t & 15, ty = t >> 4;       // c0 = tx*8, r0 = ty*8

    float acc[8][8];
#pragma unroll
    for (int i = 0; i < 8; i++)
#pragma unroll
        for (int j = 0; j < 8; j++) acc[i][j] = 0.f;

    for (int k0 = 0; k0 < 256; k0 += 16) {
#pragma unroll
        for (int i = 0; i < 8; i++) {        // A tile: As[kk][m] = x[b][k0+kk][s0+m]
            int idx = i * 256 + t;
            int m = idx & 127, kk = idx >> 7;
            As[kk][m] = x[(size_t)(b * 256 + k0 + kk) * 1024 + s0 + m];
        }
#pragma unroll
        for (int i = 0; i < 8; i++) {        // B tile: Bs[kk][n] = Wp[k0+kk][n0+n]
            int idx = i * 256 + t;
            int n = idx & 127, kk = idx >> 7;
            Bs[kk][n] = Wp[(size_t)(k0 + kk) * NQKV + n0 + n];
        }
        __syncthreads();
#pragma unroll
        for (int kk = 0; kk < 16; kk++) {
            float a[8], bbv[8];
            *(float4*)(&a[0])   = *(const float4*)(&As[kk][ty * 8]);
            *(float4*)(&a[4])   = *(const float4*)(&As[kk][ty * 8 + 4]);
            *(float4*)(&bbv[0]) = *(const float4*)(&Bs[kk][tx * 8]);
            *(float4*)(&bbv[4]) = *(const float4*)(&Bs[kk][tx * 8 + 4]);
#pragma unroll
            for (int i = 0; i < 8; i++)
#pragma unroll
                for (int j = 0; j < 8; j++)
                    acc[i][j] = fmaf(a[i], bbv[j], acc[i][j]);
        }
        __syncthreads();
    }

    // epilogue: head/type constant per tile
    const int h   = n0 / 768;
    const int rem = n0 - h * 768;
    const int tt  = rem >> 8;                 // 0=q 1=k 2=v
    const int d0  = (rem & 255) + tx * 8;     // column base for this thread
    float bias[8];
#pragma unroll
    for (int j = 0; j < 8; j++) bias[j] = bp[n0 + tx * 8 + j];

    if (tt < 2) {
        unsigned short* dst = (tt == 0 ? qb : kb) + (size_t)(b * NH + h) * SS * DK;
#pragma unroll
        for (int i = 0; i < 8; i++) {
            int s = s0 + ty * 8 + i;
            frag8 st;
#pragma unroll
            for (int j = 0; j < 8; j++) st[j] = (short)f2bf(acc[i][j] + bias[j]);
            *(frag8*)(&dst[(size_t)s * DK + d0]) = st;
        }
    } else {
        unsigned short* dst = vb + (size_t)(b * NH + h) * DK * SS;
#pragma unroll
        for (int j = 0; j < 8; j++) {
            int d = d0 + j;
            frag8 st;
#pragma unroll
            for (int i = 0; i < 8; i++) st[i] = (short)f2bf(acc[i][j] + bias[j]);
            *(frag8*)(&dst[(size_t)d * SS + s0 + ty * 8]) = st;
        }
    }
}

// ---------------------------------------------------------------------------
// K2: flash attention, bf16 MFMA. Block = 4 waves, 64 q-rows; K-tiles of 32.
// Q fragments resident in registers (8 ksteps x 8 bf16/lane per wave).
// mfma_f32_16x16x32_bf16: A[m=l&15][k=quad*8+j]; D: col=l&15,row=quad*4+reg.
// Online softmax state per row in LDS; P via LDS round-trip (m120 pattern).
// Output O as bf16 [BH,S,DK].
// ---------------------------------------------------------------------------
__global__ __launch_bounds__(256) void k2_attn(
    const unsigned short* __restrict__ qb, const unsigned short* __restrict__ kb,
    const unsigned short* __restrict__ vb, unsigned short* __restrict__ ob)
{
    __shared__ unsigned short Ks[32][264];   // 32 keys x 256 d (+8 pad)
    __shared__ unsigned short Vt[256][40];   // 256 d x 32 keys (+8 pad)
    __shared__ float          Sc[64][33];    // raw scores (scaled)
    __shared__ unsigned short Pb[64][40];    // softmaxed probs, bf16
    __shared__ float m_s[64], l_s[64], al_s[64];

    const int t    = threadIdx.x;
    const int wave = t >> 6, lane = t & 63;
    const int quad = lane >> 4, l16 = lane & 15;
    const int qt   = blockIdx.x;                       // 16 q-tiles of 64 rows
    const int bh   = blockIdx.z * NH + blockIdx.y;

    // resident Q fragments for this wave's 16 rows
    frag8 qf[8];
    {
        const int qrow = qt * 64 + wave * 16 + l16;
        const unsigned short* qp = qb + (size_t)bh * SS * DK + (size_t)qrow * DK + quad * 8;
#pragma unroll
        for (int ks = 0; ks < 8; ks++) qf[ks] = *(const frag8*)(qp + ks * 32);
    }

    f32x4 acc[16];
#pragma unroll
    for (int nb = 0; nb < 16; nb++) acc[nb] = (f32x4){0.f, 0.f, 0.f, 0.f};

    if (t < 64) { m_s[t] = -1e30f; l_s[t] = 0.f; }
    __syncthreads();

    const unsigned short* kgb = kb + (size_t)bh * SS * DK;
    const unsigned short* vgb = vb + (size_t)bh * DK * SS;

    for (int kt = 0; kt < 32; kt++) {
        // --- stage K tile (row-contig) and V tile (already transposed in global)
        {
            const unsigned short* kg = kgb + (size_t)kt * 32 * DK;
#pragma unroll
            for (int i = 0; i < 4; i++) {
                int idx = i * 256 + t;                 // ushort8 units
                int r = idx >> 5, c8 = idx & 31;
                *(frag8*)(&Ks[r][c8 * 8]) = *(const frag8*)(kg + (size_t)r * DK + c8 * 8);
            }
            const unsigned short* vg = vgb + kt * 32;
#pragma unroll
            for (int i = 0; i < 4; i++) {
                int idx = i * 256 + t;
                int d = idx >> 2, j8 = idx & 3;
                *(frag8*)(&Vt[d][j8 * 8]) = *(const frag8*)(vg + (size_t)d * SS + j8 * 8);
            }
        }
        __syncthreads();

        // --- scores: wave computes its 16 rows x 32 keys
        f32x4 sa0 = (f32x4){0.f, 0.f, 0.f, 0.f};
        f32x4 sa1 = (f32x4){0.f, 0.f, 0.f, 0.f};
#pragma unroll
        for (int ks = 0; ks < 8; ks++) {
            frag8 kf0 = *(const frag8*)(&Ks[l16][ks * 32 + quad * 8]);
            frag8 kf1 = *(const frag8*)(&Ks[16 + l16][ks * 32 + quad * 8]);
            sa0 = __builtin_amdgcn_mfma_f32_16x16x32_bf16(qf[ks], kf0, sa0, 0, 0, 0);
            sa1 = __builtin_amdgcn_mfma_f32_16x16x32_bf16(qf[ks], kf1, sa1, 0, 0, 0);
        }
#pragma unroll
        for (int r = 0; r < 4; r++) {
            Sc[wave * 16 + quad * 4 + r][l16]      = sa0[r] * SCALE;
            Sc[wave * 16 + quad * 4 + r][16 + l16] = sa1[r] * SCALE;
        }
        __syncthreads();

        // --- online softmax, one thread per row
        if (t < 64) {
            int r = t;
            float mold = m_s[r], mt = mold;
#pragma unroll
            for (int j = 0; j < 32; j++) mt = fmaxf(mt, Sc[r][j]);
            float a = __expf(mold - mt);
            float sum = 0.f;
#pragma unroll
            for (int j = 0; j < 32; j++) {
                float p = __expf(Sc[r][j] - mt);
                sum += p;
                Pb[r][j] = f2bf(p);
            }
            l_s[r] = l_s[r] * a + sum;
            m_s[r] = mt;
            al_s[r] = a;
        }
        __syncthreads();

        // --- PV: acc[nb] = alpha*acc[nb] + P_tile @ V_tile
        frag8 pf = *(const frag8*)(&Pb[wave * 16 + l16][quad * 8]);
        float av[4];
#pragma unroll
        for (int r = 0; r < 4; r++) av[r] = al_s[wave * 16 + quad * 4 + r];
#pragma unroll
        for (int nb = 0; nb < 16; nb++) {
            frag8 vf = *(const frag8*)(&Vt[nb * 16 + l16][quad * 8]);
            f32x4 c = acc[nb];
            c[0] *= av[0]; c[1] *= av[1]; c[2] *= av[2]; c[3] *= av[3];
            acc[nb] = __builtin_amdgcn_mfma_f32_16x16x32_bf16(pf, vf, c, 0, 0, 0);
        }
        __syncthreads();   // before next staging overwrites Ks/Vt
    }

    // --- epilogue: O[row][d] = acc/l, bf16
    float linv[4];
#pragma unroll
    for (int r = 0; r < 4; r++) linv[r] = 1.f / l_s[wave * 16 + quad * 4 + r];
    unsigned short* og = ob + (size_t)bh * SS * DK + (size_t)(qt * 64 + wave * 16) * DK;
#pragma unroll
    for (int nb = 0; nb < 16; nb++)
#pragma unroll
        for (int r = 0; r < 4; r++)
            og[(size_t)(quad * 4 + r) * DK + nb * 16 + l16] = f2bf(acc[nb][r] * linv[r]);
}

// ---------------------------------------------------------------------------
// K3: out = O @ Wo + bo + xt, written transposed to [B,C,S].
// A = O bf16 [BH,S,DK] viewed as [m=b*1024+s][k=h*256+d]. 128x64 tile, 8x4.
// ---------------------------------------------------------------------------
__global__ __launch_bounds__(256) void k3_proj(
    const unsigned short* __restrict__ ob, const float* __restrict__ Wo,
    const float* __restrict__ bo, const float* __restrict__ x,
    float* __restrict__ out)
{
    __shared__ float As[16][132];   // [k][m], padded
    __shared__ float Bs[16][64];
    const int t  = threadIdx.x;
    const int n0 = blockIdx.x * 64;          // 4 tiles over 256
    const int m0 = blockIdx.y * 128;         // 64 tiles over 8192
    const int b  = m0 >> 10;
    const int s0 = m0 & 1023;
    const int tx = t & 15, ty = t >> 4;      // c0 = tx*4, r0 = ty*8

    float acc[8][4];
#pragma unroll
    for (int i = 0; i < 8; i++)
#pragma unroll
        for (int j = 0; j < 4; j++) acc[i][j] = 0.f;

    for (int k0 = 0; k0 < 2048; k0 += 16) {
        const int h = k0 >> 8, d0 = k0 & 255;
        const unsigned short* ag = ob + ((size_t)(b * NH + h) * 1024 + s0) * DK + d0;
#pragma unroll
        for (int i = 0; i < 8; i++) {        // A tile (k-contig global reads)
            int idx = i * 256 + t;
            int kk = idx & 15, m = idx >> 4;
            As[kk][m] = bf2f(ag[(size_t)m * DK + kk]);
        }
#pragma unroll
        for (int i = 0; i < 4; i++) {        // B tile
            int idx = i * 256 + t;
            int n = idx & 63, kk = idx >> 6;
            Bs[kk][n] = Wo[(size_t)(k0 + kk) * 256 + n0 + n];
        }
        __syncthreads();
#pragma unroll
        for (int kk = 0; kk < 16; kk++) {
            float a[8];
            *(float4*)(&a[0]) = *(const float4*)(&As[kk][ty * 8]);
            *(float4*)(&a[4]) = *(const float4*)(&As[kk][ty * 8 + 4]);
            float4 b4 = *(const float4*)(&Bs[kk][tx * 4]);
#pragma unroll
            for (int i = 0; i < 8; i++) {
                acc[i][0] = fmaf(a[i], b4.x, acc[i][0]);
                acc[i][1] = fmaf(a[i], b4.y, acc[i][1]);
                acc[i][2] = fmaf(a[i], b4.z, acc[i][2]);
                acc[i][3] = fmaf(a[i], b4.w, acc[i][3]);
            }
        }
        __syncthreads();
    }

    // epilogue: out[b][c][s] = acc + bo[c] + x[b][c][s]
#pragma unroll
    for (int j = 0; j < 4; j++) {
        int c = n0 + tx * 4 + j;
        float bias = bo[c];
#pragma unroll
        for (int i = 0; i < 8; i++) {
            int s = s0 + ty * 8 + i;
            size_t off = ((size_t)b * 256 + c) * 1024 + s;
            out[off] = acc[i][j] + bias + x[off];
        }
    }
}

// ---------------------------------------------------------------------------
extern "C" void kernel_launch(void* const* d_in, const int* in_sizes, int n_in,
                              void* d_out, int out_size, void* d_ws, size_t ws_size,
                              hipStream_t stream)
{
    const float* x  = (const float*)d_in[0];
    const float* Wp = (const float*)d_in[1];
    const float* bp = (const float*)d_in[2];
    const float* Wo = (const float*)d_in[3];
    const float* bo = (const float*)d_in[4];
    float* out = (float*)d_out;

    // workspace: q,k,v,o bf16 buffers, 33.5 MB each (134 MB total)
    char* ws = (char*)d_ws;
    unsigned short* qb = (unsigned short*)(ws);
    unsigned short* kb = (unsigned short*)(ws + 33554432);
    unsigned short* vb = (unsigned short*)(ws + 67108864);
    unsigned short* ob = (unsigned short*)(ws + 100663296);

    dim3 g1(48, 64);
    k1_qkv<<<g1, 256, 0, stream>>>(x, Wp, bp, qb, kb, vb);
    dim3 g2(16, NH, BB);
    k2_attn<<<g2, 256, 0, stream>>>(qb, kb, vb, ob);
    dim3 g3(4, 64);
    k3_proj<<<g3, 256, 0, stream>>>(ob, Wo, bo, x, out);
}

// Round 2
// 416.408 us; speedup vs baseline: 2.1744x; 2.1744x over previous
//
#include <hip/hip_runtime.h>

// B=8, C=256, H=W=32 -> S=1024; NH=8, DK=256; qkv dim 6144.
#define NH    8
#define DK    256
#define SS    1024
#define SCALE 0.0625f

using frag8 = __attribute__((ext_vector_type(8))) short;   // 8 bf16 (4 VGPRs)
using f32x4 = __attribute__((ext_vector_type(4))) float;   // MFMA acc

__device__ __forceinline__ unsigned short f2bf(float f) {
    unsigned int u = __float_as_uint(f);
    return (unsigned short)((u + 0x7FFFu + ((u >> 16) & 1u)) >> 16);   // RNE
}

// async global->LDS, 16B per lane; LDS dest = wave-uniform base + lane*16
__device__ __forceinline__ void load_lds16(const void* g, void* l) {
    __builtin_amdgcn_global_load_lds(
        (const __attribute__((address_space(1))) unsigned int*)g,
        (__attribute__((address_space(3))) unsigned int*)l, 16, 0, 0);
}

// ---------------------------------------------------------------------------
// K0: generic transpose + fp32->bf16 convert. in: [batch][R][C] f32,
// out: [batch][C][R] bf16. grid (C/32, R/32, batch), 256 threads.
// ---------------------------------------------------------------------------
__global__ __launch_bounds__(256) void k0_t(const float* __restrict__ in,
                                            unsigned short* __restrict__ out,
                                            int R, int C)
{
    __shared__ float tile[32][33];
    const int bz = blockIdx.z;
    const int c0 = blockIdx.x * 32, r0 = blockIdx.y * 32;
    const int tx = threadIdx.x & 31, ty = threadIdx.x >> 5;   // ty 0..7
    const float* ip = in + (size_t)bz * R * C;
    unsigned short* op = out + (size_t)bz * R * C;
#pragma unroll
    for (int j = 0; j < 4; j++)
        tile[ty + j * 8][tx] = ip[(size_t)(r0 + ty + j * 8) * C + c0 + tx];
    __syncthreads();
#pragma unroll
    for (int j = 0; j < 4; j++)
        op[(size_t)(c0 + ty + j * 8) * R + r0 + tx] = f2bf(tile[tx][ty + j * 8]);
}

// ---------------------------------------------------------------------------
// K1: qkv = xt @ Wp + bp, bf16 MFMA (m97 structure). A = xb [B,S,C] bf16,
// B = Wpt [6144,256] bf16 (k-contig). 128x128 tile, BK=32, 4 waves 2x2.
// Writes q,k bf16 [BH,S,DK]; v transposed bf16 [BH,DK,S].
// n-tiles never cross head (768) or q/k/v (256) boundaries (both % 128 == 0).
// ---------------------------------------------------------------------------
__global__ __launch_bounds__(256) void k1_qkv(
    const unsigned short* __restrict__ xb, const unsigned short* __restrict__ Wpt,
    const float* __restrict__ bp,
    unsigned short* __restrict__ qb, unsigned short* __restrict__ kb,
    unsigned short* __restrict__ vb)
{
    __shared__ unsigned short As[128 * 32];   // packed row-major, 64B rows
    __shared__ unsigned short Bs[128 * 32];
    const int t = threadIdx.x;
    const int wave = t >> 6, lane = t & 63;
    const int quad = lane >> 4, l16 = lane & 15;
    const int n0 = blockIdx.x * 128, m0 = blockIdx.y * 128;
    const int b = m0 >> 10, s0 = m0 & 1023;
    const int mq = (wave >> 1) * 64, nq = (wave & 1) * 64;
    const int lr = lane >> 2, lc = (lane & 3) * 8;   // staging row/col8 in chunk

    const unsigned short* Ag = xb + (size_t)(b * 1024 + s0) * 256;
    const unsigned short* Bg = Wpt + (size_t)n0 * 256;

    f32x4 acc[4][4];
#pragma unroll
    for (int i = 0; i < 4; i++)
#pragma unroll
        for (int j = 0; j < 4; j++) acc[i][j] = (f32x4){0.f, 0.f, 0.f, 0.f};

    for (int k0 = 0; k0 < 256; k0 += 32) {
#pragma unroll
        for (int j = 0; j < 2; j++) {   // each wave stages 2 A-chunks + 2 B-chunks
            int ch = wave + j * 4;      // 16 rows each
            load_lds16(Ag + (size_t)(ch * 16 + lr) * 256 + k0 + lc, &As[ch * 512]);
            load_lds16(Bg + (size_t)(ch * 16 + lr) * 256 + k0 + lc, &Bs[ch * 512]);
        }
        __syncthreads();
        frag8 af[4], bf[4];
#pragma unroll
        for (int i = 0; i < 4; i++)
            af[i] = *(const frag8*)(&As[(mq + i * 16 + l16) * 32 + quad * 8]);
#pragma unroll
        for (int j = 0; j < 4; j++)
            bf[j] = *(const frag8*)(&Bs[(nq + j * 16 + l16) * 32 + quad * 8]);
#pragma unroll
        for (int i = 0; i < 4; i++)
#pragma unroll
            for (int j = 0; j < 4; j++)
                acc[i][j] = __builtin_amdgcn_mfma_f32_16x16x32_bf16(af[i], bf[j], acc[i][j], 0, 0, 0);
        __syncthreads();
    }

    // epilogue: head/type uniform per block
    const int h = n0 / 768;
    const int rem = n0 - h * 768;
    const int tt = rem >> 8;                    // 0=q 1=k 2=v
    const int dbase = (rem & 255) + nq;         // + j*16 + l16
    const size_t bh = (size_t)(b * NH + h);
    float bias[4];
#pragma unroll
    for (int j = 0; j < 4; j++) bias[j] = bp[n0 + nq + j * 16 + l16];

    if (tt < 2) {
        unsigned short* dst = (tt == 0 ? qb : kb) + bh * SS * DK;
#pragma unroll
        for (int i = 0; i < 4; i++)
#pragma unroll
            for (int r = 0; r < 4; r++) {
                int s = s0 + mq + i * 16 + quad * 4 + r;
#pragma unroll
                for (int j = 0; j < 4; j++)
                    dst[(size_t)s * DK + dbase + j * 16 + l16] = f2bf(acc[i][j][r] + bias[j]);
            }
    } else {
        unsigned short* dst = vb + bh * DK * SS;
#pragma unroll
        for (int j = 0; j < 4; j++) {
            int d = dbase + j * 16 + l16;
#pragma unroll
            for (int i = 0; i < 4; i++)
#pragma unroll
                for (int r = 0; r < 4; r++)
                    dst[(size_t)d * SS + s0 + mq + i * 16 + quad * 4 + r]
                        = f2bf(acc[i][j][r] + bias[j]);
        }
    }
}

// ---------------------------------------------------------------------------
// K2: flash attention. 4 waves, 64 q-rows/block, K-tiles of 32.
// Softmax fully in-register: row stats via __shfl_xor over the 16-lane quad;
// m,l,alpha in registers; P LDS round-trip is intra-wave (no barrier).
// 2 barriers/iteration. O written over qb (race-free: block-private rows).
// ---------------------------------------------------------------------------
__global__ __launch_bounds__(256) void k2_attn(
    const unsigned short* __restrict__ qb, const unsigned short* __restrict__ kb,
    const unsigned short* __restrict__ vb, unsigned short* __restrict__ ob)
{
    __shared__ unsigned short Ks[32][264];   // 32 keys x 256 d (+8 pad)
    __shared__ unsigned short Vt[256][40];   // 256 d x 32 keys (+8 pad)
    __shared__ unsigned short Pb[64][40];    // probs bf16, per-wave-private rows

    const int t = threadIdx.x;
    const int wave = t >> 6, lane = t & 63;
    const int quad = lane >> 4, l16 = lane & 15;
    const int qt = blockIdx.x;
    const int bh = blockIdx.z * NH + blockIdx.y;

    // resident Q fragments (wave's 16 rows)
    frag8 qf[8];
    {
        const int qrow = qt * 64 + wave * 16 + l16;
        const unsigned short* qp = qb + (size_t)bh * SS * DK + (size_t)qrow * DK + quad * 8;
#pragma unroll
        for (int ks = 0; ks < 8; ks++) qf[ks] = *(const frag8*)(qp + ks * 32);
    }

    f32x4 acc[16];
#pragma unroll
    for (int nb = 0; nb < 16; nb++) acc[nb] = (f32x4){0.f, 0.f, 0.f, 0.f};
    float m_run[4], l_run[4];
#pragma unroll
    for (int r = 0; r < 4; r++) { m_run[r] = -1e30f; l_run[r] = 0.f; }

    const unsigned short* kgb = kb + (size_t)bh * SS * DK;
    const unsigned short* vgb = vb + (size_t)bh * DK * SS;

    for (int kt = 0; kt < 32; kt++) {
        const unsigned short* kg = kgb + (size_t)kt * 32 * DK;
#pragma unroll
        for (int i = 0; i < 4; i++) {
            int idx = i * 256 + t;
            int r = idx >> 5, c8 = idx & 31;
            *(frag8*)(&Ks[r][c8 * 8]) = *(const frag8*)(kg + (size_t)r * DK + c8 * 8);
        }
        const unsigned short* vg = vgb + kt * 32;
#pragma unroll
        for (int i = 0; i < 4; i++) {
            int idx = i * 256 + t;
            int d = idx >> 2, j8 = idx & 3;
            *(frag8*)(&Vt[d][j8 * 8]) = *(const frag8*)(vg + (size_t)d * SS + j8 * 8);
        }
        __syncthreads();

        // scores: 16 rows x 32 keys per wave
        f32x4 sa0 = (f32x4){0.f, 0.f, 0.f, 0.f};
        f32x4 sa1 = (f32x4){0.f, 0.f, 0.f, 0.f};
#pragma unroll
        for (int ks = 0; ks < 8; ks++) {
            frag8 kf0 = *(const frag8*)(&Ks[l16][ks * 32 + quad * 8]);
            frag8 kf1 = *(const frag8*)(&Ks[16 + l16][ks * 32 + quad * 8]);
            sa0 = __builtin_amdgcn_mfma_f32_16x16x32_bf16(qf[ks], kf0, sa0, 0, 0, 0);
            sa1 = __builtin_amdgcn_mfma_f32_16x16x32_bf16(qf[ks], kf1, sa1, 0, 0, 0);
        }

        // online softmax, in-register (rows quad*4+r, 32 scores across 16 lanes x 2)
        float alpha[4];
#pragma unroll
        for (int r = 0; r < 4; r++) {
            float v0 = sa0[r] * SCALE, v1 = sa1[r] * SCALE;
            float mx = fmaxf(v0, v1);
#pragma unroll
            for (int off = 1; off < 16; off <<= 1)
                mx = fmaxf(mx, __shfl_xor(mx, off, 64));
            float mt = fmaxf(m_run[r], mx);
            alpha[r] = __expf(m_run[r] - mt);
            m_run[r] = mt;
            float p0 = __expf(v0 - mt), p1 = __expf(v1 - mt);
            float sm = p0 + p1;
#pragma unroll
            for (int off = 1; off < 16; off <<= 1)
                sm += __shfl_xor(sm, off, 64);
            l_run[r] = l_run[r] * alpha[r] + sm;
            int row = wave * 16 + quad * 4 + r;
            Pb[row][l16]      = f2bf(p0);
            Pb[row][16 + l16] = f2bf(p1);
        }

        // PV (Pb rows are wave-private: no block barrier needed before read)
        frag8 pf = *(const frag8*)(&Pb[wave * 16 + l16][quad * 8]);
#pragma unroll
        for (int nb = 0; nb < 16; nb++) {
            frag8 vf = *(const frag8*)(&Vt[nb * 16 + l16][quad * 8]);
            f32x4 c = acc[nb];
            c[0] *= alpha[0]; c[1] *= alpha[1]; c[2] *= alpha[2]; c[3] *= alpha[3];
            acc[nb] = __builtin_amdgcn_mfma_f32_16x16x32_bf16(pf, vf, c, 0, 0, 0);
        }
        __syncthreads();   // protect Ks/Vt for next staging
    }

    float linv[4];
#pragma unroll
    for (int r = 0; r < 4; r++) linv[r] = 1.f / l_run[r];
    unsigned short* og = ob + (size_t)bh * SS * DK + (size_t)(qt * 64 + wave * 16) * DK;
#pragma unroll
    for (int nb = 0; nb < 16; nb++)
#pragma unroll
        for (int r = 0; r < 4; r++)
            og[(size_t)(quad * 4 + r) * DK + nb * 16 + l16] = f2bf(acc[nb][r] * linv[r]);
}

// ---------------------------------------------------------------------------
// K3: out = O @ Wo + bo + xt (residual), bf16 MFMA, fp32 epilogue.
// A = O bf16 [BH,S,DK] (m = b*1024+s, k = h*256+d); B = Wot [256][2048] bf16.
// 128x64 tile, BK=32, 4 waves 2x2 (64x32 each). Output [B,C,S] fp32.
// ---------------------------------------------------------------------------
__global__ __launch_bounds__(256) void k3_proj(
    const unsigned short* __restrict__ ob, const unsigned short* __restrict__ Wot,
    const float* __restrict__ bo, const float* __restrict__ x,
    float* __restrict__ out)
{
    __shared__ unsigned short As[128 * 32];
    __shared__ unsigned short Bs[64 * 32];
    const int t = threadIdx.x;
    const int wave = t >> 6, lane = t & 63;
    const int quad = lane >> 4, l16 = lane & 15;
    const int n0 = blockIdx.x * 64, m0 = blockIdx.y * 128;
    const int b = m0 >> 10, s0 = m0 & 1023;
    const int mq = (wave >> 1) * 64, nq = (wave & 1) * 32;
    const int lr = lane >> 2, lc = (lane & 3) * 8;

    const unsigned short* Bg = Wot + (size_t)n0 * 2048;

    f32x4 acc[4][2];
#pragma unroll
    for (int i = 0; i < 4; i++)
#pragma unroll
        for (int j = 0; j < 2; j++) acc[i][j] = (f32x4){0.f, 0.f, 0.f, 0.f};

    for (int k0 = 0; k0 < 2048; k0 += 32) {
        const int h = k0 >> 8, d0 = k0 & 255;
        const unsigned short* Ag = ob + (size_t)((b * 8 + h) * 1024 + s0) * 256 + d0;
#pragma unroll
        for (int j = 0; j < 2; j++) {
            int ch = wave + j * 4;
            load_lds16(Ag + (size_t)(ch * 16 + lr) * 256 + lc, &As[ch * 512]);
        }
        load_lds16(Bg + (size_t)(wave * 16 + lr) * 2048 + k0 + lc, &Bs[wave * 512]);
        __syncthreads();
        frag8 af[4], bf[2];
#pragma unroll
        for (int i = 0; i < 4; i++)
            af[i] = *(const frag8*)(&As[(mq + i * 16 + l16) * 32 + quad * 8]);
#pragma unroll
        for (int j = 0; j < 2; j++)
            bf[j] = *(const frag8*)(&Bs[(nq + j * 16 + l16) * 32 + quad * 8]);
#pragma unroll
        for (int i = 0; i < 4; i++)
#pragma unroll
            for (int j = 0; j < 2; j++)
                acc[i][j] = __builtin_amdgcn_mfma_f32_16x16x32_bf16(af[i], bf[j], acc[i][j], 0, 0, 0);
        __syncthreads();
    }

    // epilogue: out[b][c][s] = acc + bo[c] + x[b][c][s]; 4 consecutive s per lane
#pragma unroll
    for (int j = 0; j < 2; j++) {
        int c = n0 + nq + j * 16 + l16;
        float bias = bo[c];
#pragma unroll
        for (int i = 0; i < 4; i++) {
            int s = s0 + mq + i * 16 + quad * 4;
            size_t off = (size_t)(b * 256 + c) * 1024 + s;
            float4 xv = *(const float4*)(&x[off]);
            float4 ov;
            ov.x = acc[i][j][0] + bias + xv.x;
            ov.y = acc[i][j][1] + bias + xv.y;
            ov.z = acc[i][j][2] + bias + xv.z;
            ov.w = acc[i][j][3] + bias + xv.w;
            *(float4*)(&out[off]) = ov;
        }
    }
}

// ---------------------------------------------------------------------------
extern "C" void kernel_launch(void* const* d_in, const int* in_sizes, int n_in,
                              void* d_out, int out_size, void* d_ws, size_t ws_size,
                              hipStream_t stream)
{
    const float* x  = (const float*)d_in[0];
    const float* Wp = (const float*)d_in[1];
    const float* bp = (const float*)d_in[2];
    const float* Wo = (const float*)d_in[3];
    const float* bo = (const float*)d_in[4];
    float* out = (float*)d_out;

    // ws layout (<= 110 MB): qb (reused as O), kb, vb, xb, Wpt, Wot
    char* ws = (char*)d_ws;
    unsigned short* qb  = (unsigned short*)(ws);
    unsigned short* kb  = (unsigned short*)(ws + 33554432);
    unsigned short* vb  = (unsigned short*)(ws + 67108864);
    unsigned short* xb  = (unsigned short*)(ws + 100663296);   // [B,S,C] bf16, 4 MB
    unsigned short* Wpt = (unsigned short*)(ws + 104857600);   // [6144,256] bf16, 3 MB
    unsigned short* Wot = (unsigned short*)(ws + 108003328);   // [256,2048] bf16, 1 MB

    k0_t<<<dim3(32, 8, 8), 256, 0, stream>>>(x, xb, 256, 1024);
    k0_t<<<dim3(192, 8, 1), 256, 0, stream>>>(Wp, Wpt, 256, 6144);
    k0_t<<<dim3(8, 64, 1), 256, 0, stream>>>(Wo, Wot, 2048, 256);
    k1_qkv<<<dim3(48, 64), 256, 0, stream>>>(xb, Wpt, bp, qb, kb, vb);
    k2_attn<<<dim3(16, NH, 8), 256, 0, stream>>>(qb, kb, vb, qb /* O over Q */);
    k3_proj<<<dim3(4, 64), 256, 0, stream>>>(qb, Wot, bo, x, out);
}